// Round 7
// baseline (1099.988 us; speedup 1.0000x reference)
//
#include <hip/hip_runtime.h>
#include <hip/hip_bf16.h>

#define B_ 16
#define S_ 2048
#define NNODE 257
#define E_ 4096
#define ETR_ 768
#define H_ 512
#define D_ 528
#define NC 3
#define NROW (B_*NNODE)   // 4112

// ---------------------------------------------------------------------------
// Generic 64x64 fp32 GEMM, C = A(MxK) @ W(KxN), all fp32.
// MODE 0: C[m,n] = acc*scale + bias[n]
// MODE 1: atomicMax(seg[(b,idx,n)], acc + bias[n])  (segment-max epilogue, N=512)
//         int-bits atomicMax on 0-initialized buffer == relu(segment_max) exactly.
// ---------------------------------------------------------------------------
template<int MODE>
__global__ __launch_bounds__(256)
void gemm64(const float* __restrict__ A, const float* __restrict__ W,
            const float* __restrict__ bias, float* __restrict__ C,
            int M, int N, int K, float scale,
            const int* __restrict__ segidx, float* __restrict__ segout)
{
    __shared__ float As[16][68];
    __shared__ float Bs[16][64];
    const int tid = threadIdx.x;
    const int tx = tid & 15, ty = tid >> 4;
    const int m0 = blockIdx.y * 64, n0 = blockIdx.x * 64;
    const int arow = tid >> 2, acol = (tid & 3) * 4;
    const int brow = tid >> 4, bcol = (tid & 15) * 4;

    float acc[4][4];
#pragma unroll
    for (int i = 0; i < 4; i++)
#pragma unroll
        for (int j = 0; j < 4; j++) acc[i][j] = 0.f;

    for (int kk = 0; kk < K; kk += 16) {
        float4 av = make_float4(0.f, 0.f, 0.f, 0.f);
        if (m0 + arow < M) av = *(const float4*)(A + (size_t)(m0 + arow) * K + kk + acol);
        As[acol + 0][arow] = av.x; As[acol + 1][arow] = av.y;
        As[acol + 2][arow] = av.z; As[acol + 3][arow] = av.w;
        float4 bv = make_float4(0.f, 0.f, 0.f, 0.f);
        if (n0 + bcol < N) bv = *(const float4*)(W + (size_t)(kk + brow) * N + n0 + bcol);
        *(float4*)&Bs[brow][bcol] = bv;
        __syncthreads();
#pragma unroll
        for (int k = 0; k < 16; k++) {
            const float4 a = *(const float4*)&As[k][ty * 4];
            const float4 b = *(const float4*)&Bs[k][tx * 4];
            const float af[4] = { a.x, a.y, a.z, a.w };
            const float bfv[4] = { b.x, b.y, b.z, b.w };
#pragma unroll
            for (int i = 0; i < 4; i++)
#pragma unroll
                for (int j = 0; j < 4; j++) acc[i][j] += af[i] * bfv[j];
        }
        __syncthreads();
    }

#pragma unroll
    for (int i = 0; i < 4; i++) {
        const int m = m0 + ty * 4 + i;
        if (m >= M) continue;
        if (MODE == 1) {
            const int bb = m >> 11;               // S_=2048
            const int idx = segidx[m];
            float* const srow = segout + (((size_t)bb * NNODE + idx) << 9);  // H_=512
#pragma unroll
            for (int j = 0; j < 4; j++) {
                const int n = n0 + tx * 4 + j;
                const float v = acc[i][j] + (bias ? bias[n] : 0.f);
                atomicMax(((int*)srow) + n, __float_as_int(v));
            }
        } else {
#pragma unroll
            for (int j = 0; j < 4; j++) {
                const int n = n0 + tx * 4 + j;
                if (n < N) {
                    const float v = acc[i][j] * scale + (bias ? bias[n] : 0.f);
                    C[(size_t)m * N + n] = v;
                }
            }
        }
    }
}

__global__ void build_x0(const float* __restrict__ seg, const int* __restrict__ ent_labels,
                         const float* __restrict__ tbl, float* __restrict__ x0)
{
    const int bn = blockIdx.x;
    const int b = bn / NNODE, n = bn % NNODE;
    for (int col = threadIdx.x; col < D_; col += blockDim.x) {
        float v;
        if (col < 16) {
            if (n == 0) v = tbl[col];
            else {
                const int lab = ent_labels[b * (NNODE - 1) + (n - 1)];
                v = (lab != 0) ? tbl[lab * 16 + col] : 0.f;
            }
        } else {
            v = (n == 0) ? 0.f : seg[(((size_t)b * NNODE + n) << 9) + (col - 16)];
        }
        x0[(size_t)bn * D_ + col] = v;
    }
}

__global__ void csr_build(const int* __restrict__ edge_index, const int* __restrict__ edge_attr,
                          float* __restrict__ degf, int* __restrict__ csr_ptr,
                          int* __restrict__ csr_edge, float* __restrict__ coef)
{
    __shared__ int cnt[NC * NNODE];
    __shared__ float dinvl[NC * NNODE];
    const int b = blockIdx.x;
    const int tid = threadIdx.x;
    const int* src = edge_index + (size_t)b * 2 * E_;
    const int* dst = src + E_;
    const int* attr = edge_attr + (size_t)b * E_;

    for (int i = tid; i < NC * NNODE; i += 256) cnt[i] = 0;
    __syncthreads();
    for (int e = tid; e < E_; e += 256) atomicAdd(&cnt[attr[e] * NNODE + dst[e]], 1);
    __syncthreads();
    for (int i = tid; i < NC * NNODE; i += 256) {
        const float d = (float)cnt[i] + 1.0f;
        degf[(size_t)b * NC * NNODE + i] = d;
        dinvl[i] = rsqrtf(d);
    }
    __syncthreads();
    if (tid == 0) {
        int run = 0;
        for (int i = 0; i < NC * NNODE; i++) { const int c = cnt[i]; cnt[i] = run; run += c; }
    }
    __syncthreads();
    for (int i = tid; i < NC * NNODE; i += 256) csr_ptr[(size_t)b * NC * NNODE + i] = cnt[i];
    __syncthreads();
    for (int e = tid; e < E_; e += 256) {
        const int a = attr[e], d = dst[e];
        const int pos = atomicAdd(&cnt[a * NNODE + d], 1);
        csr_edge[(size_t)b * E_ + pos] = e;
        coef[(size_t)b * E_ + e] = dinvl[a * NNODE + src[e]] * dinvl[a * NNODE + d];
    }
}

__global__ __launch_bounds__(256)
void gcn_gather(const float* __restrict__ h, const float* __restrict__ degf,
                const int* __restrict__ csr_ptr, const int* __restrict__ csr_edge,
                const float* __restrict__ coef, const int* __restrict__ edge_index,
                const float* __restrict__ bias, float* __restrict__ out,
                int cls, int accumulate)
{
    const int bn = blockIdx.x;
    const int b = bn / NNODE, n = bn % NNODE;
    const int tid = threadIdx.x;
    const int base = b * NC * NNODE + cls * NNODE + n;
    const float d = degf[base];
    const int start = csr_ptr[base];
    const int cnt = (int)d - 1;
    const float inv = 1.0f / d;
    const float* hrow = h + (size_t)bn * D_;
    const int c0 = tid, c1 = tid + 256, c2 = tid + 512;
    float a0 = hrow[c0] * inv + bias[c0];
    float a1 = hrow[c1] * inv + bias[c1];
    float a2 = (c2 < D_) ? hrow[c2] * inv + bias[c2] : 0.f;
    for (int i = 0; i < cnt; i++) {
        const int e = csr_edge[(size_t)b * E_ + start + i];
        const int s = edge_index[(size_t)b * 2 * E_ + e];
        const float cf = coef[(size_t)b * E_ + e];
        const float* hs = h + ((size_t)b * NNODE + s) * D_;
        a0 += cf * hs[c0];
        a1 += cf * hs[c1];
        if (c2 < D_) a2 += cf * hs[c2];
    }
    float* orow = out + (size_t)bn * D_;
    if (accumulate) {
        orow[c0] += a0; orow[c1] += a1; if (c2 < D_) orow[c2] += a2;
    } else {
        orow[c0] = a0; orow[c1] = a1; if (c2 < D_) orow[c2] = a2;
    }
}

__global__ void rowdot3(const float* __restrict__ x, const float* __restrict__ w,
                        float* __restrict__ out)
{
    const int row = blockIdx.x;
    const int lane = threadIdx.x;
    float a0 = 0.f, a1 = 0.f, a2 = 0.f;
    for (int d = lane; d < D_; d += 64) {
        const float xv = x[(size_t)row * D_ + d];
        a0 += xv * w[d * 3 + 0];
        a1 += xv * w[d * 3 + 1];
        a2 += xv * w[d * 3 + 2];
    }
#pragma unroll
    for (int off = 32; off > 0; off >>= 1) {
        a0 += __shfl_down(a0, off, 64);
        a1 += __shfl_down(a1, off, 64);
        a2 += __shfl_down(a2, off, 64);
    }
    if (lane == 0) {
        out[(size_t)row * 3 + 0] = a0;
        out[(size_t)row * 3 + 1] = a1;
        out[(size_t)row * 3 + 2] = a2;
    }
}

// cands: harness normalizes integer (incl. bool) inputs to int32.
// OUTPUT: float32 (reference returns f32; contract: "else float*").
__global__ __launch_bounds__(256)
void final_logits(const float* __restrict__ hw, const float* __restrict__ tw,
                  const int* __restrict__ cands, const float* __restrict__ b_out,
                  float* __restrict__ out)
{
    const int bi = blockIdx.x;          // b*257 + i
    const int b = bi / NNODE;
    const int j = threadIdx.x;          // 0..255
    const float h0 = hw[bi * 3 + 0], h1 = hw[bi * 3 + 1], h2 = hw[bi * 3 + 2];
    const int tj = b * NNODE + 1 + j;
    const float t0 = tw[tj * 3 + 0], t1 = tw[tj * 3 + 1], t2 = tw[tj * 3 + 2];
    const float m = (cands[(size_t)bi * NNODE + 1 + j] != 0) ? 1.f : 0.f;
    const float bo0 = b_out[0], bo1 = b_out[1], bo2 = b_out[2];
    const size_t o = ((size_t)bi * 256 + j) * 3;
    out[o + 0] = (h0 + t0) * m + bo0;
    out[o + 1] = (h1 + t1) * m + bo1;
    out[o + 2] = (h2 + t2) * m + bo2;
}

extern "C" void kernel_launch(void* const* d_in, const int* in_sizes, int n_in,
                              void* d_out, int out_size, void* d_ws, size_t ws_size,
                              hipStream_t stream)
{
    const float* emb       = (const float*)d_in[0];
    const int* ent_indices = (const int*)d_in[1];
    const int* ent_labels  = (const int*)d_in[2];
    const int* edge_index  = (const int*)d_in[3];
    const int* edge_attr   = (const int*)d_in[4];
    const int* cands       = (const int*)d_in[5];   // bool -> int32 (harness-normalized)
    const float* W_red     = (const float*)d_in[6];
    const float* b_red     = (const float*)d_in[7];
    const float* tbl       = (const float*)d_in[8];
    const float* W_gcn     = (const float*)d_in[9];
    const float* b_gcn     = (const float*)d_in[10];
    const float* W_head    = (const float*)d_in[11];
    const float* b_head    = (const float*)d_in[12];
    const float* W_tail    = (const float*)d_in[13];
    const float* b_tail    = (const float*)d_in[14];
    const float* W_out     = (const float*)d_in[15];
    const float* b_out     = (const float*)d_in[16];

    char* ws = (char*)d_ws;
    size_t off = 0;
    auto alloc = [&](size_t nbytes) -> char* {
        char* p = ws + off; off = (off + nbytes + 255) & ~(size_t)255; return p;
    };
    const size_t ROWB = (size_t)NROW * D_ * sizeof(float);     // 8.68 MB
    float* bufA = (float*)alloc(ROWB);   // seg (fp32), later h
    float* bufB = (float*)alloc(ROWB);   // x0, later x_head
    float* bufC = (float*)alloc(ROWB);   // x_cur, later x_tail
    float* bufD = (float*)alloc(ROWB);   // result accumulator
    float* degf = (float*)alloc((size_t)B_ * NC * NNODE * 4);
    float* coef = (float*)alloc((size_t)B_ * E_ * 4);
    float* hw   = (float*)alloc((size_t)NROW * 3 * 4);
    float* tw   = (float*)alloc((size_t)NROW * 3 * 4);
    int* csr_ptr  = (int*)alloc((size_t)B_ * NC * NNODE * 4);
    int* csr_edge = (int*)alloc((size_t)B_ * E_ * 4);

    // zero the segment-max buffer (0x0 == 0.0f, required by int-atomicMax trick)
    hipMemsetAsync(bufA, 0, (size_t)B_ * NNODE * H_ * sizeof(float), stream);
    hipMemsetAsync(bufD, 0, ROWB, stream);

    // 1) red = emb @ W_red + b_red, fused segment-max into bufA
    {
        dim3 grid(H_ / 64, (B_ * S_) / 64);
        gemm64<1><<<grid, 256, 0, stream>>>(
            emb, W_red, b_red, nullptr, B_ * S_, H_, ETR_, 1.f, ent_indices, bufA);
    }
    // 2) x0
    build_x0<<<NROW, 256, 0, stream>>>(bufA, ent_labels, tbl, bufB);
    // 3) CSR + deg + coef
    csr_build<<<B_, 256, 0, stream>>>(edge_index, edge_attr, degf, csr_ptr, csr_edge, coef);
    // 4) GCN: 3 classes x 2 layers
    dim3 gridG((D_ + 63) / 64, (NROW + 63) / 64);
    for (int c = 0; c < NC; c++) {
        gemm64<0><<<gridG, 256, 0, stream>>>(
            bufB, W_gcn + (size_t)(c * 2 + 0) * D_ * D_, nullptr, bufA,
            NROW, D_, D_, 1.f, nullptr, nullptr);
        gcn_gather<<<NROW, 256, 0, stream>>>(bufA, degf, csr_ptr, csr_edge, coef,
            edge_index, b_gcn + (size_t)(c * 2 + 0) * D_, bufC, c, 0);
        gemm64<0><<<gridG, 256, 0, stream>>>(
            bufC, W_gcn + (size_t)(c * 2 + 1) * D_ * D_, nullptr, bufA,
            NROW, D_, D_, 1.f, nullptr, nullptr);
        gcn_gather<<<NROW, 256, 0, stream>>>(bufA, degf, csr_ptr, csr_edge, coef,
            edge_index, b_gcn + (size_t)(c * 2 + 1) * D_, bufD, c, 1);
    }
    // 5) head / tail projections (fold the /3 into scale)
    gemm64<0><<<gridG, 256, 0, stream>>>(
        bufD, W_head, b_head, bufB, NROW, D_, D_, 1.f / 3.f, nullptr, nullptr);
    gemm64<0><<<gridG, 256, 0, stream>>>(
        bufD, W_tail, b_tail, bufC, NROW, D_, D_, 1.f / 3.f, nullptr, nullptr);
    // 6) 528 -> 3 projections
    rowdot3<<<NROW, 64, 0, stream>>>(bufB, W_out, hw);
    rowdot3<<<NROW, 64, 0, stream>>>(bufC, W_out, tw);
    // 7) final masked logits (float32 output, int32 mask)
    final_logits<<<NROW, 256, 0, stream>>>(hw, tw, cands, b_out, (float*)d_out);
}

// Round 8
// 756.142 us; speedup vs baseline: 1.4547x; 1.4547x over previous
//
#include <hip/hip_runtime.h>
#include <hip/hip_bf16.h>

typedef unsigned short u16;
typedef __attribute__((ext_vector_type(8))) short short8;
typedef __attribute__((ext_vector_type(4))) float floatx4;

#define B_ 16
#define S_ 2048
#define NNODE 257
#define E_ 4096
#define ETR_ 768
#define H_ 512
#define D_ 528
#define NC 3
#define NROW (B_*NNODE)   // 4112

#define BM 128
#define BN 64
#define BK 32
#define KP 40             // padded LDS pitch (bf16 elems): 80B rows balance banks

__device__ inline u16 f2b(float x) {
    __hip_bfloat16 h = __float2bfloat16(x);
    return *(u16*)&h;
}

__global__ void cvt_bf16(const float* __restrict__ in, u16* __restrict__ out, int n4)
{
    const int i = blockIdx.x * 256 + threadIdx.x;
    if (i < n4) {
        const float4 f = ((const float4*)in)[i];
        ushort4 o;
        o.x = f2b(f.x); o.y = f2b(f.y); o.z = f2b(f.z); o.w = f2b(f.w);
        ((ushort4*)out)[i] = o;
    }
}

// ---------------------------------------------------------------------------
// bf16 MFMA GEMM: C = A(MxK,bf16) @ W(KxN,bf16), fp32 accum.
// MODE 0: C[m,n] = acc*scale + bias[n]
// MODE 1: atomicMax(seg[(b,idx,n)], acc + bias[n])   (reduction epilogue)
// Block 128x64, 4 waves, wave w owns rows [w*32, w*32+32), all 64 cols.
// ---------------------------------------------------------------------------
template<int MODE>
__global__ __launch_bounds__(256)
void gemm_mfma(const u16* __restrict__ A, const u16* __restrict__ Wb,
               const float* __restrict__ bias, float* __restrict__ C,
               int M, int N, int K, float scale,
               const int* __restrict__ segidx, float* __restrict__ segout)
{
    __shared__ u16 As[BM][KP];      // [m][k]
    __shared__ u16 Bs[BN][KP];      // [n][k]  (transposed)
    const int tid = threadIdx.x;
    const int wave = tid >> 6, lane = tid & 63;
    const int quad = lane >> 4, l16 = lane & 15;
    const int m0 = blockIdx.y * BM, n0 = blockIdx.x * BN;

    floatx4 acc[2][4];
#pragma unroll
    for (int t = 0; t < 2; t++)
#pragma unroll
        for (int u = 0; u < 4; u++)
#pragma unroll
            for (int r = 0; r < 4; r++) acc[t][u][r] = 0.f;

    const int arow = tid >> 1, ac0 = (tid & 1) * 16;   // A stage: 128 rows x 32 k
    const int bn = tid & 63, bko = tid >> 6;           // B stage: 64 n x 4 k-octets

    for (int k0 = 0; k0 < K; k0 += BK) {
        uint4 a0 = make_uint4(0,0,0,0), a1 = make_uint4(0,0,0,0);
        const int gm = m0 + arow;
        if (gm < M && (k0 + ac0 + 16) <= K) {
            const u16* ap = A + (size_t)gm * K + k0 + ac0;
            a0 = *(const uint4*)ap;
            a1 = *(const uint4*)(ap + 8);
        }
        *(uint4*)&As[arow][ac0] = a0;
        *(uint4*)&As[arow][ac0 + 8] = a1;

        short8 bv;
#pragma unroll
        for (int j = 0; j < 8; j++) {
            const int k = k0 + bko * 8 + j;
            u16 v = 0;
            if ((n0 + bn) < N && k < K) v = Wb[(size_t)k * N + n0 + bn];
            bv[j] = (short)v;
        }
        *(short8*)&Bs[bn][bko * 8] = bv;
        __syncthreads();

        short8 af[2], bf[4];
        af[0] = *(const short8*)&As[wave * 32 + l16][quad * 8];
        af[1] = *(const short8*)&As[wave * 32 + 16 + l16][quad * 8];
#pragma unroll
        for (int u = 0; u < 4; u++) bf[u] = *(const short8*)&Bs[u * 16 + l16][quad * 8];
#pragma unroll
        for (int t = 0; t < 2; t++)
#pragma unroll
            for (int u = 0; u < 4; u++)
                acc[t][u] = __builtin_amdgcn_mfma_f32_16x16x32_bf16(af[t], bf[u], acc[t][u], 0, 0, 0);
        __syncthreads();
    }

#pragma unroll
    for (int t = 0; t < 2; t++) {
#pragma unroll
        for (int r = 0; r < 4; r++) {
            const int m = m0 + wave * 32 + t * 16 + quad * 4 + r;
            if (m >= M) continue;
            if (MODE == 1) {
                const int bb = m >> 11;               // S_=2048
                const int idx = segidx[m];
                float* const srow = segout + (((size_t)bb * NNODE + idx) << 9);
#pragma unroll
                for (int u = 0; u < 4; u++) {
                    const int n = n0 + u * 16 + l16;
                    const float v = acc[t][u][r] + (bias ? bias[n] : 0.f);
                    atomicMax(((int*)srow) + n, __float_as_int(v));
                }
            } else {
#pragma unroll
                for (int u = 0; u < 4; u++) {
                    const int n = n0 + u * 16 + l16;
                    if (n < N)
                        C[(size_t)m * N + n] = acc[t][u][r] * scale + (bias ? bias[n] : 0.f);
                }
            }
        }
    }
}

// ---------------------------------------------------------------------------
// fp32 64x64 GEMM (kept for head/tail + fallback path)
// ---------------------------------------------------------------------------
template<int MODE>
__global__ __launch_bounds__(256)
void gemm64(const float* __restrict__ A, const float* __restrict__ W,
            const float* __restrict__ bias, float* __restrict__ C,
            int M, int N, int K, float scale,
            const int* __restrict__ segidx, float* __restrict__ segout)
{
    __shared__ float Asl[16][68];
    __shared__ float Bsl[16][64];
    const int tid = threadIdx.x;
    const int tx = tid & 15, ty = tid >> 4;
    const int m0 = blockIdx.y * 64, n0 = blockIdx.x * 64;
    const int arow = tid >> 2, acol = (tid & 3) * 4;
    const int brow = tid >> 4, bcol = (tid & 15) * 4;

    float acc[4][4];
#pragma unroll
    for (int i = 0; i < 4; i++)
#pragma unroll
        for (int j = 0; j < 4; j++) acc[i][j] = 0.f;

    for (int kk = 0; kk < K; kk += 16) {
        float4 av = make_float4(0.f, 0.f, 0.f, 0.f);
        if (m0 + arow < M) av = *(const float4*)(A + (size_t)(m0 + arow) * K + kk + acol);
        Asl[acol + 0][arow] = av.x; Asl[acol + 1][arow] = av.y;
        Asl[acol + 2][arow] = av.z; Asl[acol + 3][arow] = av.w;
        float4 bv = make_float4(0.f, 0.f, 0.f, 0.f);
        if (n0 + bcol < N) bv = *(const float4*)(W + (size_t)(kk + brow) * N + n0 + bcol);
        *(float4*)&Bsl[brow][bcol] = bv;
        __syncthreads();
#pragma unroll
        for (int k = 0; k < 16; k++) {
            const float4 a = *(const float4*)&Asl[k][ty * 4];
            const float4 b = *(const float4*)&Bsl[k][tx * 4];
            const float af[4] = { a.x, a.y, a.z, a.w };
            const float bfv[4] = { b.x, b.y, b.z, b.w };
#pragma unroll
            for (int i = 0; i < 4; i++)
#pragma unroll
                for (int j = 0; j < 4; j++) acc[i][j] += af[i] * bfv[j];
        }
        __syncthreads();
    }

#pragma unroll
    for (int i = 0; i < 4; i++) {
        const int m = m0 + ty * 4 + i;
        if (m >= M) continue;
        if (MODE == 1) {
            const int bb = m >> 11;
            const int idx = segidx[m];
            float* const srow = segout + (((size_t)bb * NNODE + idx) << 9);
#pragma unroll
            for (int j = 0; j < 4; j++) {
                const int n = n0 + tx * 4 + j;
                const float v = acc[i][j] + (bias ? bias[n] : 0.f);
                atomicMax(((int*)srow) + n, __float_as_int(v));
            }
        } else {
#pragma unroll
            for (int j = 0; j < 4; j++) {
                const int n = n0 + tx * 4 + j;
                if (n < N) {
                    const float v = acc[i][j] * scale + (bias ? bias[n] : 0.f);
                    C[(size_t)m * N + n] = v;
                }
            }
        }
    }
}

// OUTB: 1 -> write bf16, 0 -> write fp32
template<int OUTB>
__global__ void build_x0(const float* __restrict__ seg, const int* __restrict__ ent_labels,
                         const float* __restrict__ tbl, float* __restrict__ x0f,
                         u16* __restrict__ x0b)
{
    const int bn = blockIdx.x;
    const int b = bn / NNODE, n = bn % NNODE;
    for (int col = threadIdx.x; col < D_; col += blockDim.x) {
        float v;
        if (col < 16) {
            if (n == 0) v = tbl[col];
            else {
                const int lab = ent_labels[b * (NNODE - 1) + (n - 1)];
                v = (lab != 0) ? tbl[lab * 16 + col] : 0.f;
            }
        } else {
            v = (n == 0) ? 0.f : seg[(((size_t)b * NNODE + n) << 9) + (col - 16)];
        }
        if (OUTB) x0b[(size_t)bn * D_ + col] = f2b(v);
        else      x0f[(size_t)bn * D_ + col] = v;
    }
}

__global__ void csr_build(const int* __restrict__ edge_index, const int* __restrict__ edge_attr,
                          float* __restrict__ degf, int* __restrict__ csr_ptr,
                          int* __restrict__ csr_edge, float* __restrict__ coef)
{
    __shared__ int cnt[NC * NNODE];
    __shared__ float dinvl[NC * NNODE];
    const int b = blockIdx.x;
    const int tid = threadIdx.x;
    const int* src = edge_index + (size_t)b * 2 * E_;
    const int* dst = src + E_;
    const int* attr = edge_attr + (size_t)b * E_;

    for (int i = tid; i < NC * NNODE; i += 256) cnt[i] = 0;
    __syncthreads();
    for (int e = tid; e < E_; e += 256) atomicAdd(&cnt[attr[e] * NNODE + dst[e]], 1);
    __syncthreads();
    for (int i = tid; i < NC * NNODE; i += 256) {
        const float d = (float)cnt[i] + 1.0f;
        degf[(size_t)b * NC * NNODE + i] = d;
        dinvl[i] = rsqrtf(d);
    }
    __syncthreads();
    if (tid == 0) {
        int run = 0;
        for (int i = 0; i < NC * NNODE; i++) { const int c = cnt[i]; cnt[i] = run; run += c; }
    }
    __syncthreads();
    for (int i = tid; i < NC * NNODE; i += 256) csr_ptr[(size_t)b * NC * NNODE + i] = cnt[i];
    __syncthreads();
    for (int e = tid; e < E_; e += 256) {
        const int a = attr[e], d = dst[e];
        const int pos = atomicAdd(&cnt[a * NNODE + d], 1);
        csr_edge[(size_t)b * E_ + pos] = e;
        coef[(size_t)b * E_ + e] = dinvl[a * NNODE + src[e]] * dinvl[a * NNODE + d];
    }
}

// OUT: 0 -> write bf16(outb); 1 -> accumulate fp32(outf); 2 -> write fp32(outf)
template<int OUT>
__global__ __launch_bounds__(256)
void gcn_gather(const float* __restrict__ h, const float* __restrict__ degf,
                const int* __restrict__ csr_ptr, const int* __restrict__ csr_edge,
                const float* __restrict__ coef, const int* __restrict__ edge_index,
                const float* __restrict__ bias, float* __restrict__ outf,
                u16* __restrict__ outb, int cls)
{
    const int bn = blockIdx.x;
    const int b = bn / NNODE, n = bn % NNODE;
    const int tid = threadIdx.x;
    const int base = b * NC * NNODE + cls * NNODE + n;
    const float d = degf[base];
    const int start = csr_ptr[base];
    const int cnt = (int)d - 1;
    const float inv = 1.0f / d;
    const float* hrow = h + (size_t)bn * D_;
    const int c0 = tid, c1 = tid + 256, c2 = tid + 512;
    float a0 = hrow[c0] * inv + bias[c0];
    float a1 = hrow[c1] * inv + bias[c1];
    float a2 = (c2 < D_) ? hrow[c2] * inv + bias[c2] : 0.f;
    for (int i = 0; i < cnt; i++) {
        const int e = csr_edge[(size_t)b * E_ + start + i];
        const int s = edge_index[(size_t)b * 2 * E_ + e];
        const float cf = coef[(size_t)b * E_ + e];
        const float* hs = h + ((size_t)b * NNODE + s) * D_;
        a0 += cf * hs[c0];
        a1 += cf * hs[c1];
        if (c2 < D_) a2 += cf * hs[c2];
    }
    if (OUT == 0) {
        u16* orow = outb + (size_t)bn * D_;
        orow[c0] = f2b(a0); orow[c1] = f2b(a1); if (c2 < D_) orow[c2] = f2b(a2);
    } else if (OUT == 1) {
        float* orow = outf + (size_t)bn * D_;
        orow[c0] += a0; orow[c1] += a1; if (c2 < D_) orow[c2] += a2;
    } else {
        float* orow = outf + (size_t)bn * D_;
        orow[c0] = a0; orow[c1] = a1; if (c2 < D_) orow[c2] = a2;
    }
}

__global__ void rowdot3(const float* __restrict__ x, const float* __restrict__ w,
                        float* __restrict__ out)
{
    const int row = blockIdx.x;
    const int lane = threadIdx.x;
    float a0 = 0.f, a1 = 0.f, a2 = 0.f;
    for (int d = lane; d < D_; d += 64) {
        const float xv = x[(size_t)row * D_ + d];
        a0 += xv * w[d * 3 + 0];
        a1 += xv * w[d * 3 + 1];
        a2 += xv * w[d * 3 + 2];
    }
#pragma unroll
    for (int off = 32; off > 0; off >>= 1) {
        a0 += __shfl_down(a0, off, 64);
        a1 += __shfl_down(a1, off, 64);
        a2 += __shfl_down(a2, off, 64);
    }
    if (lane == 0) {
        out[(size_t)row * 3 + 0] = a0;
        out[(size_t)row * 3 + 1] = a1;
        out[(size_t)row * 3 + 2] = a2;
    }
}

__global__ __launch_bounds__(256)
void final_logits(const float* __restrict__ hw, const float* __restrict__ tw,
                  const int* __restrict__ cands, const float* __restrict__ b_out,
                  float* __restrict__ out)
{
    const int bi = blockIdx.x;
    const int b = bi / NNODE;
    const int j = threadIdx.x;
    const float h0 = hw[bi * 3 + 0], h1 = hw[bi * 3 + 1], h2 = hw[bi * 3 + 2];
    const int tj = b * NNODE + 1 + j;
    const float t0 = tw[tj * 3 + 0], t1 = tw[tj * 3 + 1], t2 = tw[tj * 3 + 2];
    const float m = (cands[(size_t)bi * NNODE + 1 + j] != 0) ? 1.f : 0.f;
    const float bo0 = b_out[0], bo1 = b_out[1], bo2 = b_out[2];
    const size_t o = ((size_t)bi * 256 + j) * 3;
    out[o + 0] = (h0 + t0) * m + bo0;
    out[o + 1] = (h1 + t1) * m + bo1;
    out[o + 2] = (h2 + t2) * m + bo2;
}

extern "C" void kernel_launch(void* const* d_in, const int* in_sizes, int n_in,
                              void* d_out, int out_size, void* d_ws, size_t ws_size,
                              hipStream_t stream)
{
    const float* emb       = (const float*)d_in[0];
    const int* ent_indices = (const int*)d_in[1];
    const int* ent_labels  = (const int*)d_in[2];
    const int* edge_index  = (const int*)d_in[3];
    const int* edge_attr   = (const int*)d_in[4];
    const int* cands       = (const int*)d_in[5];
    const float* W_red     = (const float*)d_in[6];
    const float* b_red     = (const float*)d_in[7];
    const float* tbl       = (const float*)d_in[8];
    const float* W_gcn     = (const float*)d_in[9];
    const float* b_gcn     = (const float*)d_in[10];
    const float* W_head    = (const float*)d_in[11];
    const float* b_head    = (const float*)d_in[12];
    const float* W_tail    = (const float*)d_in[13];
    const float* b_tail    = (const float*)d_in[14];
    const float* W_out     = (const float*)d_in[15];
    const float* b_out     = (const float*)d_in[16];

    char* ws = (char*)d_ws;
    size_t off = 0;
    auto alloc = [&](size_t nbytes) -> char* {
        char* p = ws + off; off = (off + nbytes + 255) & ~(size_t)255; return p;
    };
    const size_t ROWB = (size_t)NROW * D_ * sizeof(float);       // 8,684,544
    const size_t ROWB2 = (size_t)NROW * D_ * sizeof(u16);        // 4,342,272

    // fast-path layout (emb_bf region reused for h/x1/xh/xt after phase 1)
    char* R0      = alloc((size_t)B_ * S_ * ETR_ * sizeof(u16)); // 50.3 MB
    u16*  emb_bf  = (u16*)R0;
    float* h      = (float*)R0;
    u16*  x1b     = (u16*)(R0 + ROWB);
    float* xh     = (float*)(R0 + ROWB + ROWB2);
    float* xt     = (float*)(R0 + ROWB + ROWB2 + ROWB);
    float* seg    = (float*)alloc((size_t)B_ * NNODE * H_ * 4);  // 8.4 MB
    u16*  x0b     = (u16*)alloc(ROWB2);
    float* result = (float*)alloc(ROWB);
    u16*  wred_bf = (u16*)alloc((size_t)ETR_ * H_ * sizeof(u16));
    u16*  wgcn_bf = (u16*)alloc((size_t)NC * 2 * D_ * D_ * sizeof(u16));
    float* degf   = (float*)alloc((size_t)B_ * NC * NNODE * 4);
    float* coef   = (float*)alloc((size_t)B_ * E_ * 4);
    float* hwp    = (float*)alloc((size_t)NROW * 3 * 4);
    float* twp    = (float*)alloc((size_t)NROW * 3 * 4);
    int* csr_ptr  = (int*)alloc((size_t)B_ * NC * NNODE * 4);
    int* csr_edge = (int*)alloc((size_t)B_ * E_ * 4);
    const bool fast = (ws_size >= off);

    if (fast) {
        const int n4e = (B_ * S_ * ETR_) / 4, n4r = (ETR_ * H_) / 4, n4g = (NC * 2 * D_ * D_) / 4;
        cvt_bf16<<<(n4e + 255) / 256, 256, 0, stream>>>(emb, emb_bf, n4e);
        cvt_bf16<<<(n4r + 255) / 256, 256, 0, stream>>>(W_red, wred_bf, n4r);
        cvt_bf16<<<(n4g + 255) / 256, 256, 0, stream>>>(W_gcn, wgcn_bf, n4g);
        hipMemsetAsync(seg, 0, (size_t)B_ * NNODE * H_ * 4, stream);
        hipMemsetAsync(result, 0, ROWB, stream);

        gemm_mfma<1><<<dim3(H_ / BN, (B_ * S_) / BM), 256, 0, stream>>>(
            emb_bf, wred_bf, b_red, nullptr, B_ * S_, H_, ETR_, 1.f, ent_indices, seg);
        build_x0<1><<<NROW, 256, 0, stream>>>(seg, ent_labels, tbl, nullptr, x0b);
        csr_build<<<B_, 256, 0, stream>>>(edge_index, edge_attr, degf, csr_ptr, csr_edge, coef);

        dim3 gmm((D_ + BN - 1) / BN, (NROW + BM - 1) / BM);   // 9 x 33
        for (int c = 0; c < NC; c++) {
            gemm_mfma<0><<<gmm, 256, 0, stream>>>(
                x0b, wgcn_bf + (size_t)(c * 2 + 0) * D_ * D_, nullptr, h,
                NROW, D_, D_, 1.f, nullptr, nullptr);
            gcn_gather<0><<<NROW, 256, 0, stream>>>(h, degf, csr_ptr, csr_edge, coef,
                edge_index, b_gcn + (size_t)(c * 2 + 0) * D_, nullptr, x1b, c);
            gemm_mfma<0><<<gmm, 256, 0, stream>>>(
                x1b, wgcn_bf + (size_t)(c * 2 + 1) * D_ * D_, nullptr, h,
                NROW, D_, D_, 1.f, nullptr, nullptr);
            gcn_gather<1><<<NROW, 256, 0, stream>>>(h, degf, csr_ptr, csr_edge, coef,
                edge_index, b_gcn + (size_t)(c * 2 + 1) * D_, result, nullptr, c);
        }
        dim3 gridG((D_ + 63) / 64, (NROW + 63) / 64);
        gemm64<0><<<gridG, 256, 0, stream>>>(result, W_head, b_head, xh,
            NROW, D_, D_, 1.f / 3.f, nullptr, nullptr);
        gemm64<0><<<gridG, 256, 0, stream>>>(result, W_tail, b_tail, xt,
            NROW, D_, D_, 1.f / 3.f, nullptr, nullptr);
        rowdot3<<<NROW, 64, 0, stream>>>(xh, W_out, hwp);
        rowdot3<<<NROW, 64, 0, stream>>>(xt, W_out, twp);
        final_logits<<<NROW, 256, 0, stream>>>(hwp, twp, cands, b_out, (float*)d_out);
        return;
    }

    // -------- fallback: proven fp32 pipeline (round-7 layout) --------
    off = 0;
    float* bufA = (float*)alloc(ROWB);
    float* bufB = (float*)alloc(ROWB);
    float* bufC = (float*)alloc(ROWB);
    float* bufD = (float*)alloc(ROWB);
    degf = (float*)alloc((size_t)B_ * NC * NNODE * 4);
    coef = (float*)alloc((size_t)B_ * E_ * 4);
    hwp  = (float*)alloc((size_t)NROW * 3 * 4);
    twp  = (float*)alloc((size_t)NROW * 3 * 4);
    csr_ptr  = (int*)alloc((size_t)B_ * NC * NNODE * 4);
    csr_edge = (int*)alloc((size_t)B_ * E_ * 4);

    hipMemsetAsync(bufA, 0, (size_t)B_ * NNODE * H_ * 4, stream);
    hipMemsetAsync(bufD, 0, ROWB, stream);
    gemm64<1><<<dim3(H_ / 64, (B_ * S_) / 64), 256, 0, stream>>>(
        emb, W_red, b_red, nullptr, B_ * S_, ETR_ == 0 ? 0 : H_, ETR_, 1.f, ent_indices, bufA);
    build_x0<0><<<NROW, 256, 0, stream>>>(bufA, ent_labels, tbl, bufB, nullptr);
    csr_build<<<B_, 256, 0, stream>>>(edge_index, edge_attr, degf, csr_ptr, csr_edge, coef);
    dim3 gridG((D_ + 63) / 64, (NROW + 63) / 64);
    for (int c = 0; c < NC; c++) {
        gemm64<0><<<gridG, 256, 0, stream>>>(bufB, W_gcn + (size_t)(c * 2 + 0) * D_ * D_,
            nullptr, bufA, NROW, D_, D_, 1.f, nullptr, nullptr);
        gcn_gather<2><<<NROW, 256, 0, stream>>>(bufA, degf, csr_ptr, csr_edge, coef,
            edge_index, b_gcn + (size_t)(c * 2 + 0) * D_, bufC, nullptr, c);
        gemm64<0><<<gridG, 256, 0, stream>>>(bufC, W_gcn + (size_t)(c * 2 + 1) * D_ * D_,
            nullptr, bufA, NROW, D_, D_, 1.f, nullptr, nullptr);
        gcn_gather<1><<<NROW, 256, 0, stream>>>(bufA, degf, csr_ptr, csr_edge, coef,
            edge_index, b_gcn + (size_t)(c * 2 + 1) * D_, bufD, nullptr, c);
    }
    gemm64<0><<<gridG, 256, 0, stream>>>(bufD, W_head, b_head, bufB,
        NROW, D_, D_, 1.f / 3.f, nullptr, nullptr);
    gemm64<0><<<gridG, 256, 0, stream>>>(bufD, W_tail, b_tail, bufC,
        NROW, D_, D_, 1.f / 3.f, nullptr, nullptr);
    rowdot3<<<NROW, 64, 0, stream>>>(bufB, W_out, hwp);
    rowdot3<<<NROW, 64, 0, stream>>>(bufC, W_out, twp);
    final_logits<<<NROW, 256, 0, stream>>>(hwp, twp, cands, b_out, (float*)d_out);
}

// Round 9
// 583.009 us; speedup vs baseline: 1.8867x; 1.2970x over previous
//
#include <hip/hip_runtime.h>
#include <hip/hip_bf16.h>

typedef unsigned short u16;
typedef __attribute__((ext_vector_type(8))) short short8;
typedef __attribute__((ext_vector_type(4))) float floatx4;

#define B_ 16
#define S_ 2048
#define NNODE 257
#define E_ 4096
#define ETR_ 768
#define H_ 512
#define D_ 528
#define NC 3
#define NROW (B_*NNODE)   // 4112
#define DD (D_*D_)

#define BM 128
#define BN 128
#define BK 32
#define KP 40             // padded LDS pitch (bf16): 80B rows spread banks

__device__ inline u16 f2b(float x) {
    __hip_bfloat16 h = __float2bfloat16(x);
    return *(u16*)&h;
}

__global__ void cvt_bf16(const float* __restrict__ in, u16* __restrict__ out, int n4)
{
    const int i = blockIdx.x * 256 + threadIdx.x;
    if (i < n4) {
        const float4 f = ((const float4*)in)[i];
        ushort4 o;
        o.x = f2b(f.x); o.y = f2b(f.y); o.z = f2b(f.z); o.w = f2b(f.w);
        ((ushort4*)out)[i] = o;
    }
}

// in f32 [R][C] (z-batched) -> out bf16 [C][R]
__global__ void transpose_cvt(const float* __restrict__ in, u16* __restrict__ out,
                              int R, int Cc, size_t instride, size_t outstride)
{
    __shared__ float t[32][33];
    const int z = blockIdx.z;
    const int tx = threadIdx.x & 31, ty = threadIdx.x >> 5;  // 32 x 8
    const int c0 = blockIdx.x * 32, r0 = blockIdx.y * 32;
    const float* ip = in + z * instride;
    u16* op = out + z * outstride;
#pragma unroll
    for (int i = 0; i < 4; i++) {
        const int r = r0 + ty + i * 8, c = c0 + tx;
        if (r < R && c < Cc) t[ty + i * 8][tx] = ip[(size_t)r * Cc + c];
    }
    __syncthreads();
#pragma unroll
    for (int i = 0; i < 4; i++) {
        const int c = c0 + ty + i * 8, r = r0 + tx;
        if (c < Cc && r < R) op[(size_t)c * R + r] = f2b(t[tx][ty + i * 8]);
    }
}

// ---------------------------------------------------------------------------
// bf16 MFMA GEMM, 128x128 tile, z-batched. A[M][K], Wt[N][K] (TRANSPOSED).
// MODE 0: C[z] = acc*scale + bias[z][n]   MODE 1: segment-max epilogue
// SWZ: XCD-locality remap for the reduction shape (gridDim.x==4).
// ---------------------------------------------------------------------------
template<int MODE, int SWZ>
__global__ __launch_bounds__(256)
void gemm_mfma(const u16* __restrict__ A, const u16* __restrict__ Wt,
               const float* __restrict__ bias_base, size_t bias_stride,
               float* __restrict__ C, int M, int N, int K, float scale,
               const int* __restrict__ segidx, float* __restrict__ segout,
               size_t astride, size_t wstride, size_t cstride)
{
    __shared__ u16 Sm[BM][KP];
    __shared__ u16 Sn[BN][KP];
    const int tid = threadIdx.x;
    const int wave = tid >> 6, lane = tid & 63;
    const int quad = lane >> 4, l16 = lane & 15;
    const int z = blockIdx.z;
    int bx = blockIdx.x, by = blockIdx.y;
    if (SWZ) {   // gridDim.x==4: keep the 4 col-blocks of a row-block on one XCD
        const int lin = blockIdx.x + (blockIdx.y << 2);
        bx = (lin >> 3) & 3;
        by = (lin & 7) + ((lin >> 5) << 3);
    }
    const int m0 = by * BM, n0 = bx * BN;

    floatx4 acc[2][8];
#pragma unroll
    for (int t = 0; t < 2; t++)
#pragma unroll
        for (int u = 0; u < 8; u++)
#pragma unroll
            for (int r = 0; r < 4; r++) acc[t][u][r] = 0.f;

    const bool isA = tid < BM;
    const int rr = isA ? tid : tid - BM;
    const int grow = isA ? (m0 + rr) : (n0 + rr);
    const bool rowok = grow < (isA ? M : N);
    const u16* gbase = isA ? (A + z * astride + (size_t)grow * K)
                           : (Wt + z * wstride + (size_t)grow * K);
    u16* lrow = isA ? &Sm[rr][0] : &Sn[rr][0];

    for (int k0 = 0; k0 < K; k0 += BK) {
#pragma unroll
        for (int s = 0; s < 4; s++) {
            uint4 v = make_uint4(0, 0, 0, 0);
            if (rowok && (k0 + s * 8 + 8) <= K) v = *(const uint4*)(gbase + k0 + s * 8);
            *(uint4*)(lrow + s * 8) = v;
        }
        __syncthreads();
        short8 af[2], bfv[8];
        af[0] = *(const short8*)&Sm[wave * 32 + l16][quad * 8];
        af[1] = *(const short8*)&Sm[wave * 32 + 16 + l16][quad * 8];
#pragma unroll
        for (int u = 0; u < 8; u++) bfv[u] = *(const short8*)&Sn[u * 16 + l16][quad * 8];
#pragma unroll
        for (int t = 0; t < 2; t++)
#pragma unroll
            for (int u = 0; u < 8; u++)
                acc[t][u] = __builtin_amdgcn_mfma_f32_16x16x32_bf16(af[t], bfv[u], acc[t][u], 0, 0, 0);
        __syncthreads();
    }

    const float* bias = bias_base ? (bias_base + z * bias_stride) : nullptr;
#pragma unroll
    for (int t = 0; t < 2; t++) {
#pragma unroll
        for (int r = 0; r < 4; r++) {
            const int m = m0 + wave * 32 + t * 16 + quad * 4 + r;
            if (m >= M) continue;
            if (MODE == 1) {
                const int bb = m >> 11;               // S_=2048
                const int idx = segidx[m];
                float* const srow = segout + (((size_t)bb * NNODE + idx) << 9);
#pragma unroll
                for (int u = 0; u < 8; u++) {
                    const int n = n0 + u * 16 + l16;
                    if (n < N) {
                        const float v = acc[t][u][r] + (bias ? bias[n] : 0.f);
                        atomicMax(((int*)srow) + n, __float_as_int(v));
                    }
                }
            } else {
#pragma unroll
                for (int u = 0; u < 8; u++) {
                    const int n = n0 + u * 16 + l16;
                    if (n < N)
                        C[z * cstride + (size_t)m * N + n] = acc[t][u][r] * scale + (bias ? bias[n] : 0.f);
                }
            }
        }
    }
}

// ---------------------------------------------------------------------------
// fp32 64x64 GEMM (fallback path only)
// ---------------------------------------------------------------------------
template<int MODE>
__global__ __launch_bounds__(256)
void gemm64(const float* __restrict__ A, const float* __restrict__ W,
            const float* __restrict__ bias, float* __restrict__ C,
            int M, int N, int K, float scale,
            const int* __restrict__ segidx, float* __restrict__ segout)
{
    __shared__ float Asl[16][68];
    __shared__ float Bsl[16][64];
    const int tid = threadIdx.x;
    const int tx = tid & 15, ty = tid >> 4;
    const int m0 = blockIdx.y * 64, n0 = blockIdx.x * 64;
    const int arow = tid >> 2, acol = (tid & 3) * 4;
    const int brow = tid >> 4, bcol = (tid & 15) * 4;

    float acc[4][4];
#pragma unroll
    for (int i = 0; i < 4; i++)
#pragma unroll
        for (int j = 0; j < 4; j++) acc[i][j] = 0.f;

    for (int kk = 0; kk < K; kk += 16) {
        float4 av = make_float4(0.f, 0.f, 0.f, 0.f);
        if (m0 + arow < M) av = *(const float4*)(A + (size_t)(m0 + arow) * K + kk + acol);
        Asl[acol + 0][arow] = av.x; Asl[acol + 1][arow] = av.y;
        Asl[acol + 2][arow] = av.z; Asl[acol + 3][arow] = av.w;
        float4 bv = make_float4(0.f, 0.f, 0.f, 0.f);
        if (n0 + bcol < N) bv = *(const float4*)(W + (size_t)(kk + brow) * N + n0 + bcol);
        *(float4*)&Bsl[brow][bcol] = bv;
        __syncthreads();
#pragma unroll
        for (int k = 0; k < 16; k++) {
            const float4 a = *(const float4*)&Asl[k][ty * 4];
            const float4 b = *(const float4*)&Bsl[k][tx * 4];
            const float af[4] = { a.x, a.y, a.z, a.w };
            const float bfv[4] = { b.x, b.y, b.z, b.w };
#pragma unroll
            for (int i = 0; i < 4; i++)
#pragma unroll
                for (int j = 0; j < 4; j++) acc[i][j] += af[i] * bfv[j];
        }
        __syncthreads();
    }

#pragma unroll
    for (int i = 0; i < 4; i++) {
        const int m = m0 + ty * 4 + i;
        if (m >= M) continue;
        if (MODE == 1) {
            const int bb = m >> 11;
            const int idx = segidx[m];
            float* const srow = segout + (((size_t)bb * NNODE + idx) << 9);
#pragma unroll
            for (int j = 0; j < 4; j++) {
                const int n = n0 + tx * 4 + j;
                const float v = acc[i][j] + (bias ? bias[n] : 0.f);
                atomicMax(((int*)srow) + n, __float_as_int(v));
            }
        } else {
#pragma unroll
            for (int j = 0; j < 4; j++) {
                const int n = n0 + tx * 4 + j;
                if (n < N) {
                    const float v = acc[i][j] * scale + (bias ? bias[n] : 0.f);
                    C[(size_t)m * N + n] = v;
                }
            }
        }
    }
}

template<int OUTB>
__global__ void build_x0(const float* __restrict__ seg, const int* __restrict__ ent_labels,
                         const float* __restrict__ tbl, float* __restrict__ x0f,
                         u16* __restrict__ x0b)
{
    const int bn = blockIdx.x;
    const int b = bn / NNODE, n = bn % NNODE;
    for (int col = threadIdx.x; col < D_; col += blockDim.x) {
        float v;
        if (col < 16) {
            if (n == 0) v = tbl[col];
            else {
                const int lab = ent_labels[b * (NNODE - 1) + (n - 1)];
                v = (lab != 0) ? tbl[lab * 16 + col] : 0.f;
            }
        } else {
            v = (n == 0) ? 0.f : seg[(((size_t)b * NNODE + n) << 9) + (col - 16)];
        }
        if (OUTB) x0b[(size_t)bn * D_ + col] = f2b(v);
        else      x0f[(size_t)bn * D_ + col] = v;
    }
}

// CSR over (class,dst) + packed {src, coef} per slot.
__global__ void csr_build(const int* __restrict__ edge_index, const int* __restrict__ edge_attr,
                          float* __restrict__ degf, int* __restrict__ csr_ptr,
                          int2* __restrict__ csr_sc)
{
    __shared__ int cnt[NC * NNODE];
    __shared__ float dinvl[NC * NNODE];
    const int b = blockIdx.x;
    const int tid = threadIdx.x;
    const int* src = edge_index + (size_t)b * 2 * E_;
    const int* dst = src + E_;
    const int* attr = edge_attr + (size_t)b * E_;

    for (int i = tid; i < NC * NNODE; i += 256) cnt[i] = 0;
    __syncthreads();
    for (int e = tid; e < E_; e += 256) atomicAdd(&cnt[attr[e] * NNODE + dst[e]], 1);
    __syncthreads();
    for (int i = tid; i < NC * NNODE; i += 256) {
        const float d = (float)cnt[i] + 1.0f;
        degf[(size_t)b * NC * NNODE + i] = d;
        dinvl[i] = rsqrtf(d);
    }
    __syncthreads();
    if (tid == 0) {
        int run = 0;
        for (int i = 0; i < NC * NNODE; i++) { const int c = cnt[i]; cnt[i] = run; run += c; }
    }
    __syncthreads();
    for (int i = tid; i < NC * NNODE; i += 256) csr_ptr[(size_t)b * NC * NNODE + i] = cnt[i];
    __syncthreads();
    for (int e = tid; e < E_; e += 256) {
        const int a = attr[e], d = dst[e], s = src[e];
        const int pos = atomicAdd(&cnt[a * NNODE + d], 1);
        const float cf = dinvl[a * NNODE + s] * dinvl[a * NNODE + d];
        csr_sc[(size_t)b * E_ + pos] = make_int2(s, __float_as_int(cf));
    }
}

// OUT: 0 bf16 write (z-strided); 1 fp32 +=; 2 fp32 =; 3 fp32 atomicAdd
template<int OUT>
__global__ __launch_bounds__(256)
void gcn_gather(const float* __restrict__ h, size_t hstride,
                const float* __restrict__ degf,
                const int* __restrict__ csr_ptr, const int2* __restrict__ csr_sc,
                const float* __restrict__ bias_base, size_t bias_stride,
                float* __restrict__ outf, u16* __restrict__ outb, size_t ostride,
                int cls0)
{
    const int bn = blockIdx.x;
    const int cls = cls0 + blockIdx.y;
    const int b = bn / NNODE, n = bn % NNODE;
    const int tid = threadIdx.x;
    const int base = b * NC * NNODE + cls * NNODE + n;
    const float d = degf[base];
    const int start = csr_ptr[base];
    const int cnt = (int)d - 1;
    const float inv = 1.0f / d;
    const float* hp = h + blockIdx.y * hstride;
    const float* bias = bias_base + cls * bias_stride;
    const float* hrow = hp + (size_t)bn * D_;
    const int c0 = tid, c1 = tid + 256, c2 = tid + 512;
    float a0 = hrow[c0] * inv + bias[c0];
    float a1 = hrow[c1] * inv + bias[c1];
    float a2 = (c2 < D_) ? hrow[c2] * inv + bias[c2] : 0.f;
    const int2* scp = csr_sc + (size_t)b * E_ + start;
    for (int i = 0; i < cnt; i++) {
        const int2 sc = scp[i];
        const float cf = __int_as_float(sc.y);
        const float* hs = hp + ((size_t)b * NNODE + sc.x) * D_;
        a0 += cf * hs[c0];
        a1 += cf * hs[c1];
        if (c2 < D_) a2 += cf * hs[c2];
    }
    if (OUT == 0) {
        u16* orow = outb + blockIdx.y * ostride + (size_t)bn * D_;
        orow[c0] = f2b(a0); orow[c1] = f2b(a1); if (c2 < D_) orow[c2] = f2b(a2);
    } else if (OUT == 1) {
        float* orow = outf + (size_t)bn * D_;
        orow[c0] += a0; orow[c1] += a1; if (c2 < D_) orow[c2] += a2;
    } else if (OUT == 2) {
        float* orow = outf + (size_t)bn * D_;
        orow[c0] = a0; orow[c1] = a1; if (c2 < D_) orow[c2] = a2;
    } else {
        float* orow = outf + (size_t)bn * D_;
        atomicAdd(&orow[c0], a0); atomicAdd(&orow[c1], a1);
        if (c2 < D_) atomicAdd(&orow[c2], a2);
    }
}

__global__ void rowdot3(const float* __restrict__ x, const float* __restrict__ w,
                        float* __restrict__ out)
{
    const int row = blockIdx.x;
    const int lane = threadIdx.x;
    float a0 = 0.f, a1 = 0.f, a2 = 0.f;
    for (int d = lane; d < D_; d += 64) {
        const float xv = x[(size_t)row * D_ + d];
        a0 += xv * w[d * 3 + 0];
        a1 += xv * w[d * 3 + 1];
        a2 += xv * w[d * 3 + 2];
    }
#pragma unroll
    for (int off = 32; off > 0; off >>= 1) {
        a0 += __shfl_down(a0, off, 64);
        a1 += __shfl_down(a1, off, 64);
        a2 += __shfl_down(a2, off, 64);
    }
    if (lane == 0) {
        out[(size_t)row * 3 + 0] = a0;
        out[(size_t)row * 3 + 1] = a1;
        out[(size_t)row * 3 + 2] = a2;
    }
}

// hw = (x/3) @ Whw + bias6[0:3];  tw = (x/3) @ Wtw + bias6[3:6]
__global__ void rowdot6(const float* __restrict__ x, const float* __restrict__ Whw,
                        const float* __restrict__ Wtw, const float* __restrict__ bias6,
                        float* __restrict__ hw, float* __restrict__ tw)
{
    const int row = blockIdx.x;
    const int lane = threadIdx.x;
    float h0 = 0.f, h1 = 0.f, h2 = 0.f, t0 = 0.f, t1 = 0.f, t2 = 0.f;
    for (int d = lane; d < D_; d += 64) {
        const float xv = x[(size_t)row * D_ + d] * (1.f / 3.f);
        h0 += xv * Whw[d * 3 + 0]; h1 += xv * Whw[d * 3 + 1]; h2 += xv * Whw[d * 3 + 2];
        t0 += xv * Wtw[d * 3 + 0]; t1 += xv * Wtw[d * 3 + 1]; t2 += xv * Wtw[d * 3 + 2];
    }
#pragma unroll
    for (int off = 32; off > 0; off >>= 1) {
        h0 += __shfl_down(h0, off, 64); h1 += __shfl_down(h1, off, 64); h2 += __shfl_down(h2, off, 64);
        t0 += __shfl_down(t0, off, 64); t1 += __shfl_down(t1, off, 64); t2 += __shfl_down(t2, off, 64);
    }
    if (lane == 0) {
        hw[(size_t)row * 3 + 0] = h0 + bias6[0];
        hw[(size_t)row * 3 + 1] = h1 + bias6[1];
        hw[(size_t)row * 3 + 2] = h2 + bias6[2];
        tw[(size_t)row * 3 + 0] = t0 + bias6[3];
        tw[(size_t)row * 3 + 1] = t1 + bias6[4];
        tw[(size_t)row * 3 + 2] = t2 + bias6[5];
    }
}

__global__ __launch_bounds__(256)
void final_logits(const float* __restrict__ hw, const float* __restrict__ tw,
                  const int* __restrict__ cands, const float* __restrict__ b_out,
                  float* __restrict__ out)
{
    const int bi = blockIdx.x;
    const int b = bi / NNODE;
    const int j = threadIdx.x;
    const float h0 = hw[bi * 3 + 0], h1 = hw[bi * 3 + 1], h2 = hw[bi * 3 + 2];
    const int tj = b * NNODE + 1 + j;
    const float t0 = tw[tj * 3 + 0], t1 = tw[tj * 3 + 1], t2 = tw[tj * 3 + 2];
    const float m = (cands[(size_t)bi * NNODE + 1 + j] != 0) ? 1.f : 0.f;
    const float bo0 = b_out[0], bo1 = b_out[1], bo2 = b_out[2];
    const size_t o = ((size_t)bi * 256 + j) * 3;
    out[o + 0] = (h0 + t0) * m + bo0;
    out[o + 1] = (h1 + t1) * m + bo1;
    out[o + 2] = (h2 + t2) * m + bo2;
}

extern "C" void kernel_launch(void* const* d_in, const int* in_sizes, int n_in,
                              void* d_out, int out_size, void* d_ws, size_t ws_size,
                              hipStream_t stream)
{
    const float* emb       = (const float*)d_in[0];
    const int* ent_indices = (const int*)d_in[1];
    const int* ent_labels  = (const int*)d_in[2];
    const int* edge_index  = (const int*)d_in[3];
    const int* edge_attr   = (const int*)d_in[4];
    const int* cands       = (const int*)d_in[5];
    const float* W_red     = (const float*)d_in[6];
    const float* b_red     = (const float*)d_in[7];
    const float* tbl       = (const float*)d_in[8];
    const float* W_gcn     = (const float*)d_in[9];
    const float* b_gcn     = (const float*)d_in[10];
    const float* W_head    = (const float*)d_in[11];
    const float* b_head    = (const float*)d_in[12];
    const float* W_tail    = (const float*)d_in[13];
    const float* b_tail    = (const float*)d_in[14];
    const float* W_out     = (const float*)d_in[15];
    const float* b_out     = (const float*)d_in[16];

    char* ws = (char*)d_ws;
    size_t off = 0;
    auto alloc = [&](size_t nbytes) -> char* {
        char* p = ws + off; off = (off + nbytes + 255) & ~(size_t)255; return p;
    };
    const size_t ROWB  = (size_t)NROW * D_ * sizeof(float);
    const size_t ROWB2 = (size_t)NROW * D_ * sizeof(u16);
    const size_t RD    = (size_t)NROW * D_;

    // region R0: emb_bf (phase 1), then h[3] + x1b[3] (GCN phases)
    char* R0      = alloc((size_t)B_ * S_ * ETR_ * sizeof(u16)); // 50.3 MB
    u16*  emb_bf  = (u16*)R0;
    float* hbuf   = (float*)R0;                                  // [3][NROW][D_] f32
    u16*  x1b     = (u16*)(R0 + 3 * ROWB);                       // [3][NROW][D_] bf16
    float* seg    = (float*)alloc((size_t)B_ * NNODE * H_ * 4);
    u16*  x0b     = (u16*)alloc(ROWB2);
    float* result = (float*)alloc(ROWB);
    u16*  wredT   = (u16*)alloc((size_t)H_ * ETR_ * sizeof(u16));    // [512][768]
    u16*  wgcnT   = (u16*)alloc((size_t)NC * 2 * DD * sizeof(u16));  // [6][528][528]
    float* Whw    = (float*)alloc((size_t)D_ * 3 * 4);
    float* Wtw    = (float*)alloc((size_t)D_ * 3 * 4);
    float* bias6  = (float*)alloc(6 * 4);
    float* degf   = (float*)alloc((size_t)B_ * NC * NNODE * 4);
    float* hwp    = (float*)alloc((size_t)NROW * 3 * 4);
    float* twp    = (float*)alloc((size_t)NROW * 3 * 4);
    int* csr_ptr  = (int*)alloc((size_t)B_ * NC * NNODE * 4);
    int2* csr_sc  = (int2*)alloc((size_t)B_ * E_ * 8);
    const bool fast = (ws_size >= off);

    if (fast) {
        const int n4e = (B_ * S_ * ETR_) / 4;
        cvt_bf16<<<(n4e + 255) / 256, 256, 0, stream>>>(emb, emb_bf, n4e);
        transpose_cvt<<<dim3(16, 24, 1), 256, 0, stream>>>(W_red, wredT, ETR_, H_, 0, 0);
        transpose_cvt<<<dim3(17, 17, 6), 256, 0, stream>>>(W_gcn, wgcnT, D_, D_, DD, DD);
        hipMemsetAsync(seg, 0, (size_t)B_ * NNODE * H_ * 4, stream);
        hipMemsetAsync(result, 0, ROWB, stream);

        // fused head/tail weights: Whw = W_head@W_out, bias6 = {b_head@W_out, b_tail@W_out}
        rowdot3<<<D_, 64, 0, stream>>>(W_head, W_out, Whw);
        rowdot3<<<D_, 64, 0, stream>>>(W_tail, W_out, Wtw);
        rowdot3<<<1, 64, 0, stream>>>(b_head, W_out, bias6);
        rowdot3<<<1, 64, 0, stream>>>(b_tail, W_out, bias6 + 3);

        // 1) reduction GEMM + fused segment-max  (SWZ requires gridDim.x==4)
        gemm_mfma<1, 1><<<dim3(H_ / BN, (B_ * S_) / BM, 1), 256, 0, stream>>>(
            emb_bf, wredT, b_red, 0, nullptr, B_ * S_, H_, ETR_, 1.f,
            ent_indices, seg, 0, 0, 0);
        build_x0<1><<<NROW, 256, 0, stream>>>(seg, ent_labels, tbl, nullptr, x0b);
        csr_build<<<B_, 256, 0, stream>>>(edge_index, edge_attr, degf, csr_ptr, csr_sc);

        // 2) GCN, class-batched (z=3)
        dim3 gmm((D_ + BN - 1) / BN, (NROW + BM - 1) / BM, NC);   // 5 x 33 x 3
        gemm_mfma<0, 0><<<gmm, 256, 0, stream>>>(
            x0b, wgcnT, nullptr, 0, hbuf, NROW, D_, D_, 1.f, nullptr, nullptr,
            0, (size_t)2 * DD, RD);
        gcn_gather<0><<<dim3(NROW, NC), 256, 0, stream>>>(
            hbuf, RD, degf, csr_ptr, csr_sc, b_gcn, (size_t)2 * D_,
            nullptr, x1b, RD, 0);
        gemm_mfma<0, 0><<<gmm, 256, 0, stream>>>(
            x1b, wgcnT + DD, nullptr, 0, hbuf, NROW, D_, D_, 1.f, nullptr, nullptr,
            RD, (size_t)2 * DD, RD);
        gcn_gather<3><<<dim3(NROW, NC), 256, 0, stream>>>(
            hbuf, RD, degf, csr_ptr, csr_sc, b_gcn + D_, (size_t)2 * D_,
            result, nullptr, 0, 0);

        // 3) fused epilogue
        rowdot6<<<NROW, 64, 0, stream>>>(result, Whw, Wtw, bias6, hwp, twp);
        final_logits<<<NROW, 256, 0, stream>>>(hwp, twp, cands, b_out, (float*)d_out);
        return;
    }

    // -------- fallback: proven fp32 pipeline --------
    off = 0;
    float* bufA = (float*)alloc(ROWB);
    float* bufB = (float*)alloc(ROWB);
    float* bufC = (float*)alloc(ROWB);
    float* bufD = (float*)alloc(ROWB);
    degf = (float*)alloc((size_t)B_ * NC * NNODE * 4);
    hwp  = (float*)alloc((size_t)NROW * 3 * 4);
    twp  = (float*)alloc((size_t)NROW * 3 * 4);
    csr_ptr = (int*)alloc((size_t)B_ * NC * NNODE * 4);
    csr_sc  = (int2*)alloc((size_t)B_ * E_ * 8);

    hipMemsetAsync(bufA, 0, (size_t)B_ * NNODE * H_ * 4, stream);
    hipMemsetAsync(bufD, 0, ROWB, stream);
    gemm64<1><<<dim3(H_ / 64, (B_ * S_) / 64), 256, 0, stream>>>(
        emb, W_red, b_red, nullptr, B_ * S_, H_, ETR_, 1.f, ent_indices, bufA);
    build_x0<0><<<NROW, 256, 0, stream>>>(bufA, ent_labels, tbl, bufB, nullptr);
    csr_build<<<B_, 256, 0, stream>>>(edge_index, edge_attr, degf, csr_ptr, csr_sc);
    dim3 gridG((D_ + 63) / 64, (NROW + 63) / 64);
    for (int c = 0; c < NC; c++) {
        gemm64<0><<<gridG, 256, 0, stream>>>(bufB, W_gcn + (size_t)(c * 2 + 0) * DD,
            nullptr, bufA, NROW, D_, D_, 1.f, nullptr, nullptr);
        gcn_gather<2><<<dim3(NROW, 1), 256, 0, stream>>>(bufA, 0, degf, csr_ptr, csr_sc,
            b_gcn, (size_t)2 * D_, bufC, nullptr, 0, c);
        gemm64<0><<<gridG, 256, 0, stream>>>(bufC, W_gcn + (size_t)(c * 2 + 1) * DD,
            nullptr, bufA, NROW, D_, D_, 1.f, nullptr, nullptr);
        gcn_gather<1><<<dim3(NROW, 1), 256, 0, stream>>>(bufA, 0, degf, csr_ptr, csr_sc,
            b_gcn + D_, (size_t)2 * D_, bufD, nullptr, 0, c);
    }
    gemm64<0><<<gridG, 256, 0, stream>>>(bufD, W_head, b_head, bufB,
        NROW, D_, D_, 1.f / 3.f, nullptr, nullptr);
    gemm64<0><<<gridG, 256, 0, stream>>>(bufD, W_tail, b_tail, bufC,
        NROW, D_, D_, 1.f / 3.f, nullptr, nullptr);
    rowdot3<<<NROW, 64, 0, stream>>>(bufB, W_out, hwp);
    rowdot3<<<NROW, 64, 0, stream>>>(bufC, W_out, twp);
    final_logits<<<NROW, 256, 0, stream>>>(hwp, twp, cands, b_out, (float*)d_out);
}